// Round 2
// baseline (989.789 us; speedup 1.0000x reference)
//
#include <hip/hip_runtime.h>

// diag-embed: out[i, j, j] = x[i, j], zeros elsewhere.
// x: [8192, 176] fp32; out: [8192, 176, 176] fp32 (~1.015 GB).
// Pure write-BW-bound: one 16B store per thread, non-temporal
// (output >> L2, no reuse). All index math 32-bit (63.4M vec elems < 2^31).

#define D_MODEL 176
#define ROW_VEC (D_MODEL / 4)   // 44 float4 per output row

typedef float fvec4 __attribute__((ext_vector_type(4)));  // native vec: OK for nontemporal builtin

__global__ __launch_bounds__(256) void diag_embed_kernel(
    const float* __restrict__ x,
    fvec4* __restrict__ out,
    unsigned int total_vec) {
    unsigned int idx = blockIdx.x * 256u + threadIdx.x;
    if (idx >= total_vec) return;

    // idx -> (output row, float4-position-in-row)
    unsigned int row = idx / ROW_VEC;             // magic-mul, cheap
    unsigned int pos = idx - row * ROW_VEC;       // 0..43
    unsigned int j   = row % D_MODEL;             // diagonal column for this row
    unsigned int i   = row / D_MODEL;             // batch index

    fvec4 v = (fvec4)(0.f, 0.f, 0.f, 0.f);
    unsigned int c0 = pos * 4u;                   // first column this float4 covers
    unsigned int off = j - c0;                    // unsigned trick: in-range iff < 4
    if (off < 4u) {
        float val = x[i * D_MODEL + j];
        v[off] = val;
    }
    __builtin_nontemporal_store(v, &out[idx]);
}

extern "C" void kernel_launch(void* const* d_in, const int* in_sizes, int n_in,
                              void* d_out, int out_size, void* d_ws, size_t ws_size,
                              hipStream_t stream) {
    const float* x = (const float*)d_in[0];
    fvec4* out = (fvec4*)d_out;

    unsigned int total_vec = (unsigned int)(out_size / 4);  // 63,438,848
    unsigned int grid = (total_vec + 255u) / 256u;          // 247,808 blocks

    diag_embed_kernel<<<grid, 256, 0, stream>>>(x, out, total_vec);
}